// Round 17
// baseline (224.726 us; speedup 1.0000x reference)
//
#include <hip/hip_runtime.h>
#include <hip/hip_bf16.h>

typedef __hip_bfloat16 bf16;
typedef __attribute__((ext_vector_type(4))) float f32x4;
typedef __attribute__((ext_vector_type(8))) short s16x8;
typedef __attribute__((ext_vector_type(4))) unsigned short u16x4;

#define NB 64
#define NT 197
#define DIM 768
#define NH 12
#define HQKV 3072
#define DH 1536
#define DV 128
#define MREAL (NB*NT)      // 12608
#define MPAD 12800         // 50*256
#define KPAD 224           // padded key count
#define PSTR 232           // P-tile LDS row stride
#define CNT ((float)MREAL)

__device__ __forceinline__ float bf2f(bf16 v) { return __bfloat162float(v); }
__device__ __forceinline__ bf16  f2bf(float v){ return __float2bfloat16(v); }
__device__ __forceinline__ unsigned short f2bfu(float v){ return __builtin_bit_cast(unsigned short, __float2bfloat16(v)); }
__device__ __forceinline__ float u2f(unsigned short u){ return __builtin_bit_cast(float, (unsigned)u << 16); }

// async global->LDS, 16B per lane; LDS dest wave-uniform base (HW adds lane*16)
__device__ __forceinline__ void async16(const bf16* g, bf16* l) {
  __builtin_amdgcn_global_load_lds((const __attribute__((address_space(1))) void*)g,
                                   (__attribute__((address_space(3))) void*)l, 16, 0, 0);
}

// ---------------- prep: vectorized f32->bf16 converts, zero pads/stats/cls ----------------
__global__ void prep_kernel(const float* __restrict__ x, const float* __restrict__ qkv_w,
                            const float* __restrict__ proj_w,
                            bf16* __restrict__ xb, bf16* __restrict__ wqkvb,
                            bf16* __restrict__ wprojb, bf16* __restrict__ act,
                            bf16* __restrict__ vT,
                            float* __restrict__ statq, float* __restrict__ statp,
                            float* __restrict__ cls)
{
  const int stride = gridDim.x * blockDim.x;
  const int tid = blockIdx.x * blockDim.x + threadIdx.x;
  const u16x4 z4 = {0,0,0,0};
  for (int i = tid; i < MREAL*DIM/4; i += stride) {
    float4 v = ((const float4*)x)[i];
    u16x4 o = {f2bfu(v.x), f2bfu(v.y), f2bfu(v.z), f2bfu(v.w)};
    ((u16x4*)xb)[i] = o;
  }
  for (int i = tid; i < (MPAD-MREAL)*DIM/4; i += stride)
    ((u16x4*)(xb + (size_t)MREAL*DIM))[i] = z4;
  for (int i = tid; i < HQKV*DIM/4; i += stride) {
    float4 v = ((const float4*)qkv_w)[i];
    u16x4 o = {f2bfu(v.x), f2bfu(v.y), f2bfu(v.z), f2bfu(v.w)};
    ((u16x4*)wqkvb)[i] = o;
  }
  for (int i = tid; i < DIM*DH/4; i += stride) {
    float4 v = ((const float4*)proj_w)[i];
    u16x4 o = {f2bfu(v.x), f2bfu(v.y), f2bfu(v.z), f2bfu(v.w)};
    ((u16x4*)wprojb)[i] = o;
  }
  for (int i = tid; i < (MPAD-MREAL)*DH/4; i += stride)
    ((u16x4*)(act + (size_t)MREAL*DH))[i] = z4;
  // zero V^T pad columns (keys 197..223)
  for (int i = tid; i < NB*NH*DV*(KPAD-NT); i += stride) {
    int r = i / (KPAD-NT), c = NT + (i - r*(KPAD-NT));
    vT[(size_t)r*KPAD + c] = f2bf(0.f);
  }
  for (int i = tid; i < 2*HQKV; i += stride) statq[i] = 0.f;
  for (int i = tid; i < 2*DIM;  i += stride) statp[i] = 0.f;
  for (int i = tid; i < NB*(NT-1); i += stride) cls[i] = 0.f;
}

// ---------------- GEMM A (qkv): 256x256 tile, BK=64, 8 waves, 2-phase counted vmcnt ----
// Per-wave tile 128x64 -> FLOP/LDS-read-byte = 42.7 (vs 32 at 64x64): attacks the LDS-BW
// bound that capped all 128^2 variants at ~25% MfmaUtil. Sync = R15-proven cheap 2-phase:
// stage(kt+1) -> vmcnt(8) -> barrier -> reads+MFMA (B-frags reused across both m-halves)
// -> barrier. R11-proven 128B-row XOR involution (8 lanes/4-bank group = conflict-free).
// Supertile 5bm x 6bn = 30 blocks (ws 4.3 MB ~ L2) under chunked XCD swizzle.
// VT: col-tile == one head; wc 0/1 -> q/k to C, wc 2/3 -> V^T transpose.
template<int K, int NT_TILES, bool VT, bool SWZ>
__global__ __launch_bounds__(512, 1)
void gemm256(const bf16* __restrict__ A, const bf16* __restrict__ Bw,
             bf16* __restrict__ C, bf16* __restrict__ vT,
             float* __restrict__ stats, int Ncols, int nblk)
{
  constexpr int NKT = K/64;
  __shared__ bf16 As[2][256*64];   // 64 KB
  __shared__ bf16 Bs[2][256*64];   // 64 KB
  int bid = blockIdx.x;
  if (SWZ) {                       // bijective XCD swizzle (m204): chunk per XCD
    const int q = nblk >> 3, r = nblk & 7;
    const int xcd = bid & 7, idx = bid >> 3;
    bid = (xcd < r ? xcd*(q+1) : r*(q+1) + (xcd-r)*q) + idx;
  }
  // supertile decomposition: 30 blocks = 5 bm x 6 bn (qkv: 50 x 12 grid = 20 supertiles)
  int bm, bn;
  {
    const int sup = bid / 30, w = bid % 30;
    const int bmS = sup % 10, bnS = sup / 10;
    bm = bmS*5 + w/6;
    bn = bnS*6 + w%6;
  }
  const int t = threadIdx.x;
  const int wave = t >> 6, lane = t & 63;
  const int wr = wave >> 2, wc = wave & 3;
  const int l15 = lane & 15, l4 = lane >> 4;

  // staging: thread t -> row sr (0..63) of each 64-row chunk, source granule pre-swizzled
  const int sr = t >> 3;
  const int scol = ((t & 7) ^ (sr & 7)) * 8;
  const bf16* aS = A  + (size_t)(bm*256 + sr)*K + scol;
  const bf16* bS = Bw + (size_t)(bn*256 + sr)*K + scol;
  const int ldsOff = wave * 512;   // elems; HW adds lane*16B

  auto stage = [&](int slot, int kt) {
#pragma unroll
    for (int i = 0; i < 4; ++i) {
      async16(aS + kt*64 + (size_t)(i*64)*K, &As[slot][i*4096 + ldsOff]);
      async16(bS + kt*64 + (size_t)(i*64)*K, &Bs[slot][i*4096 + ldsOff]);
    }
  };

  f32x4 acc[8][4] = {};
  stage(0, 0);
  const int rswz = l15 & 7;
  for (int kt = 0; kt < NKT; ++kt) {
    if (kt + 1 < NKT) {
      stage((kt + 1) & 1, kt + 1);                       // disjoint slot from compute
      asm volatile("s_waitcnt vmcnt(8)" ::: "memory");   // kt's 8 landed; kt+1 in flight
    } else {
      asm volatile("s_waitcnt vmcnt(0)" ::: "memory");
    }
    __builtin_amdgcn_s_barrier();
    asm volatile("" ::: "memory");

    const bf16* as = As[kt & 1];
    const bf16* bs = Bs[kt & 1];
#pragma unroll
    for (int ks = 0; ks < 2; ++ks) {
      const int rg = ((ks*4 + l4) ^ rswz) * 8;
      s16x8 af[8], bfr[4];
#pragma unroll
      for (int m = 0; m < 8; ++m)
        af[m]  = *(const s16x8*)&as[(wr*128 + m*16 + l15)*64 + rg];
#pragma unroll
      for (int n = 0; n < 4; ++n)
        bfr[n] = *(const s16x8*)&bs[(wc*64 + n*16 + l15)*64 + rg];
      __builtin_amdgcn_s_setprio(1);
#pragma unroll
      for (int m = 0; m < 8; ++m)
#pragma unroll
        for (int n = 0; n < 4; ++n)
          acc[m][n] = __builtin_amdgcn_mfma_f32_16x16x32_bf16(af[m], bfr[n], acc[m][n], 0, 0, 0);
      __builtin_amdgcn_s_setprio(0);
    }
    asm volatile("" ::: "memory");
    __builtin_amdgcn_s_barrier();   // all waves done reading slot kt&1
    asm volatile("" ::: "memory");
  }

  // ---------------- epilogue (R13-proven 256-wide variant) ----------------
  const int gRow0 = bm*256 + wr*128;
  const int colBase = bn*256 + wc*64;
#pragma unroll
  for (int n = 0; n < 4; ++n) {
    const int col = colBase + n*16 + l15;
    float s = 0.f, sq = 0.f;
    if (!VT || wc < 2) {      // plain C write (q/k half of head)
#pragma unroll
      for (int m = 0; m < 8; ++m) {
        const int r0 = gRow0 + m*16 + l4*4;
        const bool wrk = r0 < MREAL;   // r0%4==0, MREAL%4==0 -> whole group real
#pragma unroll
        for (int j = 0; j < 4; ++j) {
          float v = acc[m][n][j];
          s += v; sq += v*v;
          if (wrk) C[(size_t)(r0 + j)*Ncols + col] = f2bf(v);
        }
      }
    } else {                  // V^T transpose write: head == bn, d = within-head col - 128
      const int d = wc*64 + n*16 + l15 - 128;
#pragma unroll
      for (int m = 0; m < 8; ++m) {
        const int r0 = gRow0 + m*16 + l4*4;
#pragma unroll
        for (int j = 0; j < 4; ++j) { float v = acc[m][n][j]; s += v; sq += v*v; }
        if (r0 < MREAL) {
          int b2 = r0 / 197;
          int n0 = r0 - b2*197;
          if (n0 <= NT-4) {
            bf16* dst = vT + ((size_t)((b2*NH + bn)*DV + d))*KPAD + n0;
#pragma unroll
            for (int j = 0; j < 4; ++j) dst[j] = f2bf(acc[m][n][j]);
          } else {
#pragma unroll
            for (int j = 0; j < 4; ++j) {
              int r = r0 + j; int b3 = r / 197; int nn = r - b3*197;
              vT[((size_t)((b3*NH + bn)*DV + d))*KPAD + nn] = f2bf(acc[m][n][j]);
            }
          }
        }
      }
    }
    s  += __shfl_xor(s, 16);  s  += __shfl_xor(s, 32);
    sq += __shfl_xor(sq, 16); sq += __shfl_xor(sq, 32);
    if (l4 == 0) { atomicAdd(&stats[col], s); atomicAdd(&stats[Ncols + col], sq); }
  }
}

// ---------------- GEMM B (proj): BK=32, 4 blocks/CU, counted vmcnt (R12-proven) --------
template<int K, int NT_TILES, bool SWZ>
__global__ __launch_bounds__(256, 4)
void gemm32(const bf16* __restrict__ A, const bf16* __restrict__ Bw,
            bf16* __restrict__ C, float* __restrict__ stats, int Ncols, int nblk)
{
  constexpr int NKT = K/32;
  __shared__ bf16 As[2][128*32];   // 16 KB
  __shared__ bf16 Bs[2][128*32];   // 16 KB
  int bid = blockIdx.x;
  if (SWZ) {                       // bijective XCD swizzle (m204)
    const int q = nblk >> 3, r = nblk & 7;
    const int xcd = bid & 7, idx = bid >> 3;
    bid = (xcd < r ? xcd*(q+1) : r*(q+1) + (xcd-r)*q) + idx;
  }
  const int bn = bid % NT_TILES;
  const int bm = bid / NT_TILES;
  const int t = threadIdx.x;
  const int wave = t >> 6, lane = t & 63;
  const int wm = wave >> 1, wn = wave & 1;
  const int l15 = lane & 15, l4 = lane >> 4;

  const int sr = t >> 2;
  const bf16* aG = A  + (size_t)(bm*128 + sr)*K + (t&3)*8;
  const bf16* bG = Bw + (size_t)(bn*128 + sr)*K + (t&3)*8;
  const int ldsOff = wave * 512;   // elems; HW adds lane*16B

  auto stage = [&](int slot, int kt) {
    async16(aG + kt*32,                &As[slot][ldsOff]);
    async16(aG + kt*32 + (size_t)64*K, &As[slot][ldsOff + 2048]);
    async16(bG + kt*32,                &Bs[slot][ldsOff]);
    async16(bG + kt*32 + (size_t)64*K, &Bs[slot][ldsOff + 2048]);
  };

  f32x4 acc[4][4] = {};
  stage(0, 0);
  for (int kt = 0; kt < NKT; ++kt) {
    if (kt + 1 < NKT) {
      stage((kt + 1) & 1, kt + 1);
      asm volatile("s_waitcnt vmcnt(4)" ::: "memory");
    } else {
      asm volatile("s_waitcnt vmcnt(0)" ::: "memory");
    }
    __builtin_amdgcn_s_barrier();
    asm volatile("" ::: "memory");

    const bf16* as = As[kt & 1];
    const bf16* bs = Bs[kt & 1];
    s16x8 af[4], bfr[4];
#pragma unroll
    for (int i = 0; i < 4; ++i) af[i]  = *(const s16x8*)&as[(wm*64 + i*16 + l15)*32 + l4*8];
#pragma unroll
    for (int i = 0; i < 4; ++i) bfr[i] = *(const s16x8*)&bs[(wn*64 + i*16 + l15)*32 + l4*8];
    __builtin_amdgcn_s_setprio(1);
#pragma unroll
    for (int im = 0; im < 4; ++im)
#pragma unroll
      for (int in = 0; in < 4; ++in)
        acc[im][in] = __builtin_amdgcn_mfma_f32_16x16x32_bf16(af[im], bfr[in], acc[im][in], 0, 0, 0);
    __builtin_amdgcn_s_setprio(0);
    asm volatile("" ::: "memory");
    __builtin_amdgcn_s_barrier();
    asm volatile("" ::: "memory");
  }

  const int gRow0 = bm*128 + wm*64;
  const int colBase = bn*128 + wn*64;
#pragma unroll
  for (int n = 0; n < 4; ++n) {
    const int col = colBase + n*16 + l15;
    float s = 0.f, sq = 0.f;
#pragma unroll
    for (int m = 0; m < 4; ++m) {
      const int r0 = gRow0 + m*16 + l4*4;
      const bool wr = r0 < MREAL;
#pragma unroll
      for (int j = 0; j < 4; ++j) {
        float v = acc[m][n][j];
        s += v; sq += v*v;
        if (wr) C[(size_t)(r0 + j)*Ncols + col] = f2bf(v);
      }
    }
    s  += __shfl_xor(s, 16);  s  += __shfl_xor(s, 32);
    sq += __shfl_xor(sq, 16); sq += __shfl_xor(sq, 32);
    if (l4 == 0) { atomicAdd(&stats[col], s); atomicAdd(&stats[Ncols + col], sq); }
  }
}

// ---------------- BN stats -> scale/bias; for qkv also emit per-head (c,w) fold vectors ----
__global__ void finalize_stats(const float* __restrict__ stats, const float* __restrict__ g,
                               const float* __restrict__ bb, float* __restrict__ sb, int F,
                               float* __restrict__ qcw)
{
  int f = blockIdx.x * blockDim.x + threadIdx.x;
  if (f >= F) return;
  float m   = stats[f] / CNT;
  float var = stats[F + f] / CNT - m*m;
  float scl = g[f] / sqrtf(var + 1e-5f);
  float bia = bb[f] - m*scl;
  sb[f] = scl;
  sb[F + f] = bia;
  if (qcw && (f & 255) < 64) {          // q-feature: pair with k-feature f+64
    float mk   = stats[f + 64] / CNT;
    float vark = stats[F + f + 64] / CNT - mk*mk;
    float sclk = g[f + 64] / sqrtf(vark + 1e-5f);
    int h = f >> 8, d = f & 63;
    qcw[h*128 + d]      = 0.125f * scl * sclk;   // c_d
    qcw[h*128 + 64 + d] = 0.125f * bia * sclk;   // w_d
  }
}

// ---------------- attention v10: K,V^T staged in LDS once per (b,h); 8 waves ----------------
__global__ __launch_bounds__(512, 1)
void attn_kernel(const bf16* __restrict__ qkv, const bf16* __restrict__ vT,
                 const float* __restrict__ sb, const float* __restrict__ qcw,
                 bf16* __restrict__ act, float* __restrict__ cls)
{
  __shared__ bf16 k_lds[KPAD*64];     // 28 KB
  __shared__ bf16 v_lds[DV*256];      // 64 KB
  __shared__ bf16 p_all[8*16*PSTR];   // 59.4 KB
  const int t = threadIdx.x;
  const int wave = t >> 6, lane = t & 63;
  const int l15 = lane & 15, l4 = lane >> 4;
  const int bh = blockIdx.x;
  const int b = bh / NH, h = bh - b*NH;
  const size_t rowBase = (size_t)b * NT;
  bf16* p_lds = &p_all[wave * (16*PSTR)];
  const bf16* Qp = qkv + rowBase*HQKV + h*256;
  const bf16* Kp = Qp + 64;
  const bf16* Vp = vT + (size_t)bh*DV*KPAD;
  const int fv = h*256 + 128;

  {
    const int ldsW = wave * 512;
#pragma unroll
    for (int p = 0; p < 4; ++p) {
      int lam = p*512 + t;
      if (lam < KPAD*8) {
        int row = lam >> 3, g = lam & 7;
        async16(Kp + (size_t)row*HQKV + ((g ^ (row & 7))*8), &k_lds[p*4096 + ldsW]);
      }
    }
#pragma unroll
    for (int p = 0; p < 8; ++p) {
      int lam = p*512 + t;
      int r = lam >> 5, sl = lam & 31;
      async16(Vp + (size_t)r*KPAD + ((sl ^ (r & 7))*8), &v_lds[p*4096 + ldsW]);
    }
  }
  __syncthreads();

  f32x4 c0a = *(const f32x4*)&qcw[h*128 + l4*8],      c0b = *(const f32x4*)&qcw[h*128 + l4*8 + 4];
  f32x4 w0a = *(const f32x4*)&qcw[h*128 + 64 + l4*8], w0b = *(const f32x4*)&qcw[h*128 + 64 + l4*8 + 4];
  f32x4 c1a = *(const f32x4*)&qcw[h*128 + 32 + l4*8], c1b = *(const f32x4*)&qcw[h*128 + 32 + l4*8 + 4];
  f32x4 w1a = *(const f32x4*)&qcw[h*128 + 96 + l4*8], w1b = *(const f32x4*)&qcw[h*128 + 96 + l4*8 + 4];

  const int kswz = l15 & 7;

  for (int ti = wave; ti < 13; ti += 8) {
    const int q0 = ti * 16;

    s16x8 aq0 = *(const s16x8*)&Qp[(size_t)(q0 + l15)*HQKV + l4*8];
    s16x8 aq1 = *(const s16x8*)&Qp[(size_t)(q0 + l15)*HQKV + 32 + l4*8];
    {
      s16x8 r0, r1;
#pragma unroll
      for (int j = 0; j < 4; ++j) {
        r0[j]   = (short)f2bfu(u2f((unsigned short)aq0[j])   * c0a[j] + w0a[j]);
        r0[j+4] = (short)f2bfu(u2f((unsigned short)aq0[j+4]) * c0b[j] + w0b[j]);
        r1[j]   = (short)f2bfu(u2f((unsigned short)aq1[j])   * c1a[j] + w1a[j]);
        r1[j+4] = (short)f2bfu(u2f((unsigned short)aq1[j+4]) * c1b[j] + w1b[j]);
      }
      aq0 = r0; aq1 = r1;
    }

    f32x4 scr[14];
#pragma unroll
    for (int kt = 0; kt < 14; ++kt) {
      const int krow = (kt*16 + l15)*64;
      s16x8 bk0 = *(const s16x8*)&k_lds[krow + ((l4 ^ kswz)*8)];
      s16x8 bk1 = *(const s16x8*)&k_lds[krow + (((4 + l4) ^ kswz)*8)];
      f32x4 z = {};
      z = __builtin_amdgcn_mfma_f32_16x16x32_bf16(aq0, bk0, z, 0, 0, 0);
      scr[kt] = __builtin_amdgcn_mfma_f32_16x16x32_bf16(aq1, bk1, z, 0, 0, 0);
    }

    float mx[4] = {-1e30f, -1e30f, -1e30f, -1e30f}, sm[4];
#pragma unroll
    for (int kt = 0; kt < 14; ++kt) {
      int colv = kt*16 + l15;
#pragma unroll
      for (int j = 0; j < 4; ++j) {
        if (colv >= NT) scr[kt][j] = -1e30f;
        mx[j] = fmaxf(mx[j], scr[kt][j]);
      }
    }
#pragma unroll
    for (int j = 0; j < 4; ++j) {
      mx[j] = fmaxf(mx[j], __shfl_xor(mx[j], 1));
      mx[j] = fmaxf(mx[j], __shfl_xor(mx[j], 2));
      mx[j] = fmaxf(mx[j], __shfl_xor(mx[j], 4));
      mx[j] = fmaxf(mx[j], __shfl_xor(mx[j], 8));
      sm[j] = 0.f;
    }
#pragma unroll
    for (int kt = 0; kt < 14; ++kt)
#pragma unroll
      for (int j = 0; j < 4; ++j) { float e = __expf(scr[kt][j] - mx[j]); scr[kt][j] = e; sm[j] += e; }
#pragma unroll
    for (int j = 0; j < 4; ++j) {
      sm[j] += __shfl_xor(sm[j], 1);
      sm[j] += __shfl_xor(sm[j], 2);
      sm[j] += __shfl_xor(sm[j], 4);
      sm[j] += __shfl_xor(sm[j], 8);
      sm[j] = 1.f / sm[j];
    }
    if (ti == 0 && l4 == 0) {
#pragma unroll
      for (int kt = 0; kt < 14; ++kt) {
        int colv = kt*16 + l15;
        if (colv >= 1 && colv < NT)
          atomicAdd(&cls[b*(NT-1) + colv - 1], scr[kt][0] * sm[0] * (1.f/NH));
      }
    }
#pragma unroll
    for (int kt = 0; kt < 14; ++kt) {
      int colv = kt*16 + l15;
#pragma unroll
      for (int j = 0; j < 4; ++j)
        p_lds[(l4*4 + j)*PSTR + colv] = f2bf(scr[kt][j] * sm[j]);
    }

    f32x4 ao[8] = {};
#pragma unroll
    for (int ks = 0; ks < 7; ++ks) {
      s16x8 ap = *(const s16x8*)&p_lds[l15*PSTR + ks*32 + l4*8];
#pragma unroll
      for (int dt = 0; dt < 8; ++dt) {
        const int vrow = (dt*16 + l15)*256;
        s16x8 bv = *(const s16x8*)&v_lds[vrow + (((ks*4 + l4) ^ kswz)*8)];
        ao[dt] = __builtin_amdgcn_mfma_f32_16x16x32_bf16(ap, bv, ao[dt], 0, 0, 0);
      }
    }
#pragma unroll
    for (int dt = 0; dt < 8; ++dt) {
      const int d = dt*16 + l15;
      const float av = sb[fv + d];
      const float bv = sb[HQKV + fv + d];
#pragma unroll
      for (int j = 0; j < 4; ++j) {
        int q = q0 + l4*4 + j;
        if (q < NT) {
          float v = ao[dt][j] * av + bv;
          float hs = v * fminf(fmaxf(v + 3.f, 0.f), 6.f) * (1.f/6.f);
          act[(rowBase + q)*DH + h*DV + d] = f2bf(hs);
        }
      }
    }
  }
}

// ---------------- final BN apply -> f32 out ----------------
__global__ void apply_bn(const bf16* __restrict__ y, const float* __restrict__ sb,
                         float* __restrict__ out)
{
  const int stride = gridDim.x * blockDim.x;
  for (int i = blockIdx.x * blockDim.x + threadIdx.x; i < MREAL*DIM/4; i += stride) {
    int c = (i*4) % DIM;
    u16x4 yv = *(const u16x4*)&y[(size_t)i*4];
    float4 o;
    o.x = u2f(yv.x) * sb[c]     + sb[DIM + c];
    o.y = u2f(yv.y) * sb[c + 1] + sb[DIM + c + 1];
    o.z = u2f(yv.z) * sb[c + 2] + sb[DIM + c + 2];
    o.w = u2f(yv.w) * sb[c + 3] + sb[DIM + c + 3];
    *(float4*)&out[(size_t)i*4] = o;
  }
}

extern "C" void kernel_launch(void* const* d_in, const int* in_sizes, int n_in,
                              void* d_out, int out_size, void* d_ws, size_t ws_size,
                              hipStream_t stream)
{
  const float* x      = (const float*)d_in[0];
  const float* qkv_w  = (const float*)d_in[1];
  const float* qkv_g  = (const float*)d_in[2];
  const float* qkv_b  = (const float*)d_in[3];
  const float* proj_w = (const float*)d_in[4];
  const float* proj_g = (const float*)d_in[5];
  const float* proj_b = (const float*)d_in[6];
  float* y_out   = (float*)d_out;
  float* cls_out = y_out + (size_t)MREAL * DIM;

  char* ws = (char*)d_ws;
  size_t off = 0;
  auto alloc = [&](size_t bytes) { void* p = ws + off; off += (bytes + 255) & ~(size_t)255; return p; };
  bf16* xb      = (bf16*)alloc((size_t)MPAD * DIM * 2);
  bf16* wqkvb   = (bf16*)alloc((size_t)HQKV * DIM * 2);
  bf16* wprojb  = (bf16*)alloc((size_t)DIM * DH * 2);
  bf16* qkv_raw = (bf16*)alloc((size_t)MPAD * HQKV * 2);
  bf16* act     = (bf16*)alloc((size_t)MPAD * DH * 2);
  bf16* y_raw   = (bf16*)alloc((size_t)MPAD * DIM * 2);
  bf16* vT      = (bf16*)alloc((size_t)NB * NH * DV * KPAD * 2);
  float* statq  = (float*)alloc((size_t)2 * HQKV * 4);
  float* sbq    = (float*)alloc((size_t)2 * HQKV * 4);
  float* statp  = (float*)alloc((size_t)2 * DIM * 4);
  float* sbp    = (float*)alloc((size_t)2 * DIM * 4);
  float* qcw    = (float*)alloc((size_t)NH * 128 * 4);

  prep_kernel<<<2048, 256, 0, stream>>>(x, qkv_w, proj_w, xb, wqkvb, wprojb, act, vT,
                                        statq, statp, cls_out);
  // qkv GEMM: 50 x 12 = 600 blocks, 256^2 tile @ 1 block/CU, 2-phase counted vmcnt
  gemm256<DIM, HQKV/256, true, true><<<(MPAD/256)*(HQKV/256), 512, 0, stream>>>(
      xb, wqkvb, qkv_raw, vT, statq, HQKV, (MPAD/256)*(HQKV/256));
  finalize_stats<<<HQKV/256, 256, 0, stream>>>(statq, qkv_g, qkv_b, sbq, HQKV, qcw);
  // attention: one block per (b,h) = 768 blocks, K/V staged in LDS once per block
  attn_kernel<<<NB*NH, 512, 0, stream>>>(qkv_raw, vT, sbq, qcw, act, cls_out);
  // proj GEMM: 600 blocks, BK=32 @ 4 blocks/CU (all co-resident)
  gemm32<DH, DIM/128, true><<<(MPAD/128)*(DIM/128), 256, 0, stream>>>(
      act, wprojb, y_raw, statp, DIM, (MPAD/128)*(DIM/128));
  finalize_stats<<<DIM/256, 256, 0, stream>>>(statp, proj_g, proj_b, sbp, DIM, nullptr);
  apply_bn<<<2048, 256, 0, stream>>>(y_raw, sbp, y_out);
}

// Round 18
// 218.489 us; speedup vs baseline: 1.0285x; 1.0285x over previous
//
#include <hip/hip_runtime.h>
#include <hip/hip_bf16.h>

typedef __hip_bfloat16 bf16;
typedef __attribute__((ext_vector_type(4))) float f32x4;
typedef __attribute__((ext_vector_type(8))) short s16x8;
typedef __attribute__((ext_vector_type(4))) unsigned short u16x4;

#define NB 64
#define NT 197
#define DIM 768
#define NH 12
#define HQKV 3072
#define DH 1536
#define DV 128
#define MREAL (NB*NT)      // 12608
#define MPAD 12800         // 100*128
#define KPAD 224           // padded key count
#define PSTR 232           // P-tile LDS row stride
#define CNT ((float)MREAL)

__device__ __forceinline__ float bf2f(bf16 v) { return __bfloat162float(v); }
__device__ __forceinline__ bf16  f2bf(float v){ return __float2bfloat16(v); }
__device__ __forceinline__ unsigned short f2bfu(float v){ return __builtin_bit_cast(unsigned short, __float2bfloat16(v)); }
__device__ __forceinline__ float u2f(unsigned short u){ return __builtin_bit_cast(float, (unsigned)u << 16); }

// async global->LDS, 16B per lane; LDS dest wave-uniform base (HW adds lane*16)
__device__ __forceinline__ void async16(const bf16* g, bf16* l) {
  __builtin_amdgcn_global_load_lds((const __attribute__((address_space(1))) void*)g,
                                   (__attribute__((address_space(3))) void*)l, 16, 0, 0);
}

// ---------------- prep: vectorized f32->bf16 converts, zero pads/stats/cls ----------------
__global__ void prep_kernel(const float* __restrict__ x, const float* __restrict__ qkv_w,
                            const float* __restrict__ proj_w,
                            bf16* __restrict__ xb, bf16* __restrict__ wqkvb,
                            bf16* __restrict__ wprojb, bf16* __restrict__ act,
                            bf16* __restrict__ vT,
                            float* __restrict__ statq, float* __restrict__ statp,
                            float* __restrict__ cls)
{
  const int stride = gridDim.x * blockDim.x;
  const int tid = blockIdx.x * blockDim.x + threadIdx.x;
  const u16x4 z4 = {0,0,0,0};
  for (int i = tid; i < MREAL*DIM/4; i += stride) {
    float4 v = ((const float4*)x)[i];
    u16x4 o = {f2bfu(v.x), f2bfu(v.y), f2bfu(v.z), f2bfu(v.w)};
    ((u16x4*)xb)[i] = o;
  }
  for (int i = tid; i < (MPAD-MREAL)*DIM/4; i += stride)
    ((u16x4*)(xb + (size_t)MREAL*DIM))[i] = z4;
  for (int i = tid; i < HQKV*DIM/4; i += stride) {
    float4 v = ((const float4*)qkv_w)[i];
    u16x4 o = {f2bfu(v.x), f2bfu(v.y), f2bfu(v.z), f2bfu(v.w)};
    ((u16x4*)wqkvb)[i] = o;
  }
  for (int i = tid; i < DIM*DH/4; i += stride) {
    float4 v = ((const float4*)proj_w)[i];
    u16x4 o = {f2bfu(v.x), f2bfu(v.y), f2bfu(v.z), f2bfu(v.w)};
    ((u16x4*)wprojb)[i] = o;
  }
  for (int i = tid; i < (MPAD-MREAL)*DH/4; i += stride)
    ((u16x4*)(act + (size_t)MREAL*DH))[i] = z4;
  // zero V^T pad columns (keys 197..223)
  for (int i = tid; i < NB*NH*DV*(KPAD-NT); i += stride) {
    int r = i / (KPAD-NT), c = NT + (i - r*(KPAD-NT));
    vT[(size_t)r*KPAD + c] = f2bf(0.f);
  }
  for (int i = tid; i < 2*HQKV; i += stride) statq[i] = 0.f;
  for (int i = tid; i < 2*DIM;  i += stride) statp[i] = 0.f;
  for (int i = tid; i < NB*(NT-1); i += stride) cls[i] = 0.f;
}

// ---------------- GEMM A (qkv): BK=64, 2 blocks/CU, XOR swizzle, counted vmcnt ----------
// + L2-fitting supertile order: 4 bm x 12 bn = 48 blocks -> working set 4x196KB A +
// 12x196KB B = 3.1 MB <= 4 MB per-XCD L2. Best-measured qkv config (R16: 95.7 us).
template<int K, int NT_TILES, bool VT, bool SWZ>
__global__ __launch_bounds__(256, 2)
void gemm64(const bf16* __restrict__ A, const bf16* __restrict__ Bw,
            bf16* __restrict__ C, bf16* __restrict__ vT,
            float* __restrict__ stats, int Ncols, int nblk)
{
  constexpr int NKT = K/64;
  __shared__ bf16 As[2][128*64];   // 32 KB
  __shared__ bf16 Bs[2][128*64];   // 32 KB
  int bid = blockIdx.x;
  if (SWZ) {                       // bijective XCD swizzle (m204): chunk per XCD
    const int q = nblk >> 3, r = nblk & 7;
    const int xcd = bid & 7, idx = bid >> 3;
    bid = (xcd < r ? xcd*(q+1) : r*(q+1) + (xcd-r)*q) + idx;
  }
  // supertile decomposition: 48 blocks = 4 bm x 12 bn; supertiles bn-super-major
  int bn, bm;
  {
    const int sup = bid / 48, w = bid % 48;
    const int bnS = sup / 25, bmS = sup % 25;   // 2 x 25 supertiles (2400 blocks)
    bm = bmS*4 + w/12;
    bn = bnS*12 + w%12;
  }
  const int t = threadIdx.x;
  const int wave = t >> 6, lane = t & 63;
  const int wm = wave >> 1, wn = wave & 1;
  const int l15 = lane & 15, l4 = lane >> 4;

  // staging: thread t covers row sr = t>>3 (+i*32), source col granule pre-swizzled
  const int sr = t >> 3;
  const int scol = ((t & 7) ^ (sr & 7)) * 8;
  const bf16* aG = A  + (size_t)(bm*128 + sr)*K + scol;
  const bf16* bG = Bw + (size_t)(bn*128 + sr)*K + scol;
  const int ldsOff = wave * 512;   // elems; HW adds lane*16B

  auto stage = [&](int slot, int kt) {
#pragma unroll
    for (int i = 0; i < 4; ++i) {
      async16(aG + kt*64 + (size_t)(i*32)*K, &As[slot][i*2048 + ldsOff]);
      async16(bG + kt*64 + (size_t)(i*32)*K, &Bs[slot][i*2048 + ldsOff]);
    }
  };

  f32x4 acc[4][4] = {};
  stage(0, 0);
  const int rswz = l15 & 7;
  for (int kt = 0; kt < NKT; ++kt) {
    if (kt + 1 < NKT) {
      stage((kt + 1) & 1, kt + 1);                       // disjoint slot from compute
      asm volatile("s_waitcnt vmcnt(8)" ::: "memory");   // kt's 8 landed; kt+1 in flight
    } else {
      asm volatile("s_waitcnt vmcnt(0)" ::: "memory");
    }
    __builtin_amdgcn_s_barrier();
    asm volatile("" ::: "memory");

    const bf16* as = As[kt & 1];
    const bf16* bs = Bs[kt & 1];
#pragma unroll
    for (int ks = 0; ks < 2; ++ks) {
      s16x8 af[4], bfr[4];
#pragma unroll
      for (int i = 0; i < 4; ++i)
        af[i]  = *(const s16x8*)&as[(wm*64 + i*16 + l15)*64 + (((ks*4 + l4) ^ rswz)*8)];
#pragma unroll
      for (int i = 0; i < 4; ++i)
        bfr[i] = *(const s16x8*)&bs[(wn*64 + i*16 + l15)*64 + (((ks*4 + l4) ^ rswz)*8)];
      __builtin_amdgcn_s_setprio(1);
#pragma unroll
      for (int im = 0; im < 4; ++im)
#pragma unroll
        for (int in = 0; in < 4; ++in)
          acc[im][in] = __builtin_amdgcn_mfma_f32_16x16x32_bf16(af[im], bfr[in], acc[im][in], 0, 0, 0);
      __builtin_amdgcn_s_setprio(0);
    }
    asm volatile("" ::: "memory");
    __builtin_amdgcn_s_barrier();   // all waves done reading slot kt&1
    asm volatile("" ::: "memory");
  }

  // ---------------- epilogue: C write (+stats) or V^T transpose (+stats) ----------------
  const int gRow0 = bm*128 + wm*64;
  const int colBase = bn*128 + wn*64;
  if (!VT || (bn & 1) == 0) {
#pragma unroll
    for (int n = 0; n < 4; ++n) {
      const int col = colBase + n*16 + l15;
      float s = 0.f, sq = 0.f;
#pragma unroll
      for (int m = 0; m < 4; ++m) {
        const int r0 = gRow0 + m*16 + l4*4;
        const bool wr = r0 < MREAL;   // r0%4==0, MREAL%4==0 -> whole group real
#pragma unroll
        for (int j = 0; j < 4; ++j) {
          float v = acc[m][n][j];
          s += v; sq += v*v;
          if (wr) C[(size_t)(r0 + j)*Ncols + col] = f2bf(v);
        }
      }
      s  += __shfl_xor(s, 16);  s  += __shfl_xor(s, 32);
      sq += __shfl_xor(sq, 16); sq += __shfl_xor(sq, 32);
      if (l4 == 0) { atomicAdd(&stats[col], s); atomicAdd(&stats[Ncols + col], sq); }
    }
  } else {
    const int hh = bn >> 1;   // head index (v half-tile)
#pragma unroll
    for (int n = 0; n < 4; ++n) {
      const int col = colBase + n*16 + l15;
      const int d = col & 127;
      float s = 0.f, sq = 0.f;
#pragma unroll
      for (int m = 0; m < 4; ++m) {
        const int r0 = gRow0 + m*16 + l4*4;
#pragma unroll
        for (int j = 0; j < 4; ++j) { float v = acc[m][n][j]; s += v; sq += v*v; }
        if (r0 < MREAL) {
          int b2 = r0 / 197;
          int n0 = r0 - b2*197;
          if (n0 <= NT-4) {
            bf16* dst = vT + ((size_t)((b2*NH + hh)*DV + d))*KPAD + n0;
#pragma unroll
            for (int j = 0; j < 4; ++j) dst[j] = f2bf(acc[m][n][j]);
          } else {
#pragma unroll
            for (int j = 0; j < 4; ++j) {
              int r = r0 + j; int b3 = r / 197; int nn = r - b3*197;
              vT[((size_t)((b3*NH + hh)*DV + d))*KPAD + nn] = f2bf(acc[m][n][j]);
            }
          }
        }
      }
      s  += __shfl_xor(s, 16);  s  += __shfl_xor(s, 32);
      sq += __shfl_xor(sq, 16); sq += __shfl_xor(sq, 32);
      if (l4 == 0) { atomicAdd(&stats[col], s); atomicAdd(&stats[Ncols + col], sq); }
    }
  }
}

// ---------------- GEMM B (proj): BK=32, 4 blocks/CU, counted vmcnt (R12-proven) --------
template<int K, int NT_TILES, bool SWZ>
__global__ __launch_bounds__(256, 4)
void gemm32(const bf16* __restrict__ A, const bf16* __restrict__ Bw,
            bf16* __restrict__ C, float* __restrict__ stats, int Ncols, int nblk)
{
  constexpr int NKT = K/32;
  __shared__ bf16 As[2][128*32];   // 16 KB
  __shared__ bf16 Bs[2][128*32];   // 16 KB
  int bid = blockIdx.x;
  if (SWZ) {                       // bijective XCD swizzle (m204)
    const int q = nblk >> 3, r = nblk & 7;
    const int xcd = bid & 7, idx = bid >> 3;
    bid = (xcd < r ? xcd*(q+1) : r*(q+1) + (xcd-r)*q) + idx;
  }
  const int bn = bid % NT_TILES;
  const int bm = bid / NT_TILES;
  const int t = threadIdx.x;
  const int wave = t >> 6, lane = t & 63;
  const int wm = wave >> 1, wn = wave & 1;
  const int l15 = lane & 15, l4 = lane >> 4;

  const int sr = t >> 2;
  const bf16* aG = A  + (size_t)(bm*128 + sr)*K + (t&3)*8;
  const bf16* bG = Bw + (size_t)(bn*128 + sr)*K + (t&3)*8;
  const int ldsOff = wave * 512;   // elems; HW adds lane*16B

  auto stage = [&](int slot, int kt) {
    async16(aG + kt*32,                &As[slot][ldsOff]);
    async16(aG + kt*32 + (size_t)64*K, &As[slot][ldsOff + 2048]);
    async16(bG + kt*32,                &Bs[slot][ldsOff]);
    async16(bG + kt*32 + (size_t)64*K, &Bs[slot][ldsOff + 2048]);
  };

  f32x4 acc[4][4] = {};
  stage(0, 0);
  for (int kt = 0; kt < NKT; ++kt) {
    if (kt + 1 < NKT) {
      stage((kt + 1) & 1, kt + 1);
      asm volatile("s_waitcnt vmcnt(4)" ::: "memory");
    } else {
      asm volatile("s_waitcnt vmcnt(0)" ::: "memory");
    }
    __builtin_amdgcn_s_barrier();
    asm volatile("" ::: "memory");

    const bf16* as = As[kt & 1];
    const bf16* bs = Bs[kt & 1];
    s16x8 af[4], bfr[4];
#pragma unroll
    for (int i = 0; i < 4; ++i) af[i]  = *(const s16x8*)&as[(wm*64 + i*16 + l15)*32 + l4*8];
#pragma unroll
    for (int i = 0; i < 4; ++i) bfr[i] = *(const s16x8*)&bs[(wn*64 + i*16 + l15)*32 + l4*8];
    __builtin_amdgcn_s_setprio(1);
#pragma unroll
    for (int im = 0; im < 4; ++im)
#pragma unroll
      for (int in = 0; in < 4; ++in)
        acc[im][in] = __builtin_amdgcn_mfma_f32_16x16x32_bf16(af[im], bfr[in], acc[im][in], 0, 0, 0);
    __builtin_amdgcn_s_setprio(0);
    asm volatile("" ::: "memory");
    __builtin_amdgcn_s_barrier();
    asm volatile("" ::: "memory");
  }

  const int gRow0 = bm*128 + wm*64;
  const int colBase = bn*128 + wn*64;
#pragma unroll
  for (int n = 0; n < 4; ++n) {
    const int col = colBase + n*16 + l15;
    float s = 0.f, sq = 0.f;
#pragma unroll
    for (int m = 0; m < 4; ++m) {
      const int r0 = gRow0 + m*16 + l4*4;
      const bool wr = r0 < MREAL;
#pragma unroll
      for (int j = 0; j < 4; ++j) {
        float v = acc[m][n][j];
        s += v; sq += v*v;
        if (wr) C[(size_t)(r0 + j)*Ncols + col] = f2bf(v);
      }
    }
    s  += __shfl_xor(s, 16);  s  += __shfl_xor(s, 32);
    sq += __shfl_xor(sq, 16); sq += __shfl_xor(sq, 32);
    if (l4 == 0) { atomicAdd(&stats[col], s); atomicAdd(&stats[Ncols + col], sq); }
  }
}

// ---------------- BN stats -> scale/bias; for qkv also emit per-head (c,w) fold vectors ----
__global__ void finalize_stats(const float* __restrict__ stats, const float* __restrict__ g,
                               const float* __restrict__ bb, float* __restrict__ sb, int F,
                               float* __restrict__ qcw)
{
  int f = blockIdx.x * blockDim.x + threadIdx.x;
  if (f >= F) return;
  float m   = stats[f] / CNT;
  float var = stats[F + f] / CNT - m*m;
  float scl = g[f] / sqrtf(var + 1e-5f);
  float bia = bb[f] - m*scl;
  sb[f] = scl;
  sb[F + f] = bia;
  if (qcw && (f & 255) < 64) {          // q-feature: pair with k-feature f+64
    float mk   = stats[f + 64] / CNT;
    float vark = stats[F + f + 64] / CNT - mk*mk;
    float sclk = g[f + 64] / sqrtf(vark + 1e-5f);
    int h = f >> 8, d = f & 63;
    qcw[h*128 + d]      = 0.125f * scl * sclk;   // c_d
    qcw[h*128 + 64 + d] = 0.125f * bia * sclk;   // w_d
  }
}

// ---------------- attention v10: K,V^T staged in LDS once per (b,h); 8 waves ----------------
__global__ __launch_bounds__(512, 1)
void attn_kernel(const bf16* __restrict__ qkv, const bf16* __restrict__ vT,
                 const float* __restrict__ sb, const float* __restrict__ qcw,
                 bf16* __restrict__ act, float* __restrict__ cls)
{
  __shared__ bf16 k_lds[KPAD*64];     // 28 KB
  __shared__ bf16 v_lds[DV*256];      // 64 KB
  __shared__ bf16 p_all[8*16*PSTR];   // 59.4 KB
  const int t = threadIdx.x;
  const int wave = t >> 6, lane = t & 63;
  const int l15 = lane & 15, l4 = lane >> 4;
  const int bh = blockIdx.x;
  const int b = bh / NH, h = bh - b*NH;
  const size_t rowBase = (size_t)b * NT;
  bf16* p_lds = &p_all[wave * (16*PSTR)];
  const bf16* Qp = qkv + rowBase*HQKV + h*256;
  const bf16* Kp = Qp + 64;
  const bf16* Vp = vT + (size_t)bh*DV*KPAD;
  const int fv = h*256 + 128;

  {
    const int ldsW = wave * 512;
#pragma unroll
    for (int p = 0; p < 4; ++p) {
      int lam = p*512 + t;
      if (lam < KPAD*8) {
        int row = lam >> 3, g = lam & 7;
        async16(Kp + (size_t)row*HQKV + ((g ^ (row & 7))*8), &k_lds[p*4096 + ldsW]);
      }
    }
#pragma unroll
    for (int p = 0; p < 8; ++p) {
      int lam = p*512 + t;
      int r = lam >> 5, sl = lam & 31;
      async16(Vp + (size_t)r*KPAD + ((sl ^ (r & 7))*8), &v_lds[p*4096 + ldsW]);
    }
  }
  __syncthreads();

  f32x4 c0a = *(const f32x4*)&qcw[h*128 + l4*8],      c0b = *(const f32x4*)&qcw[h*128 + l4*8 + 4];
  f32x4 w0a = *(const f32x4*)&qcw[h*128 + 64 + l4*8], w0b = *(const f32x4*)&qcw[h*128 + 64 + l4*8 + 4];
  f32x4 c1a = *(const f32x4*)&qcw[h*128 + 32 + l4*8], c1b = *(const f32x4*)&qcw[h*128 + 32 + l4*8 + 4];
  f32x4 w1a = *(const f32x4*)&qcw[h*128 + 96 + l4*8], w1b = *(const f32x4*)&qcw[h*128 + 96 + l4*8 + 4];

  const int kswz = l15 & 7;

  for (int ti = wave; ti < 13; ti += 8) {
    const int q0 = ti * 16;

    s16x8 aq0 = *(const s16x8*)&Qp[(size_t)(q0 + l15)*HQKV + l4*8];
    s16x8 aq1 = *(const s16x8*)&Qp[(size_t)(q0 + l15)*HQKV + 32 + l4*8];
    {
      s16x8 r0, r1;
#pragma unroll
      for (int j = 0; j < 4; ++j) {
        r0[j]   = (short)f2bfu(u2f((unsigned short)aq0[j])   * c0a[j] + w0a[j]);
        r0[j+4] = (short)f2bfu(u2f((unsigned short)aq0[j+4]) * c0b[j] + w0b[j]);
        r1[j]   = (short)f2bfu(u2f((unsigned short)aq1[j])   * c1a[j] + w1a[j]);
        r1[j+4] = (short)f2bfu(u2f((unsigned short)aq1[j+4]) * c1b[j] + w1b[j]);
      }
      aq0 = r0; aq1 = r1;
    }

    f32x4 scr[14];
#pragma unroll
    for (int kt = 0; kt < 14; ++kt) {
      const int krow = (kt*16 + l15)*64;
      s16x8 bk0 = *(const s16x8*)&k_lds[krow + ((l4 ^ kswz)*8)];
      s16x8 bk1 = *(const s16x8*)&k_lds[krow + (((4 + l4) ^ kswz)*8)];
      f32x4 z = {};
      z = __builtin_amdgcn_mfma_f32_16x16x32_bf16(aq0, bk0, z, 0, 0, 0);
      scr[kt] = __builtin_amdgcn_mfma_f32_16x16x32_bf16(aq1, bk1, z, 0, 0, 0);
    }

    float mx[4] = {-1e30f, -1e30f, -1e30f, -1e30f}, sm[4];
#pragma unroll
    for (int kt = 0; kt < 14; ++kt) {
      int colv = kt*16 + l15;
#pragma unroll
      for (int j = 0; j < 4; ++j) {
        if (colv >= NT) scr[kt][j] = -1e30f;
        mx[j] = fmaxf(mx[j], scr[kt][j]);
      }
    }
#pragma unroll
    for (int j = 0; j < 4; ++j) {
      mx[j] = fmaxf(mx[j], __shfl_xor(mx[j], 1));
      mx[j] = fmaxf(mx[j], __shfl_xor(mx[j], 2));
      mx[j] = fmaxf(mx[j], __shfl_xor(mx[j], 4));
      mx[j] = fmaxf(mx[j], __shfl_xor(mx[j], 8));
      sm[j] = 0.f;
    }
#pragma unroll
    for (int kt = 0; kt < 14; ++kt)
#pragma unroll
      for (int j = 0; j < 4; ++j) { float e = __expf(scr[kt][j] - mx[j]); scr[kt][j] = e; sm[j] += e; }
#pragma unroll
    for (int j = 0; j < 4; ++j) {
      sm[j] += __shfl_xor(sm[j], 1);
      sm[j] += __shfl_xor(sm[j], 2);
      sm[j] += __shfl_xor(sm[j], 4);
      sm[j] += __shfl_xor(sm[j], 8);
      sm[j] = 1.f / sm[j];
    }
    if (ti == 0 && l4 == 0) {
#pragma unroll
      for (int kt = 0; kt < 14; ++kt) {
        int colv = kt*16 + l15;
        if (colv >= 1 && colv < NT)
          atomicAdd(&cls[b*(NT-1) + colv - 1], scr[kt][0] * sm[0] * (1.f/NH));
      }
    }
#pragma unroll
    for (int kt = 0; kt < 14; ++kt) {
      int colv = kt*16 + l15;
#pragma unroll
      for (int j = 0; j < 4; ++j)
        p_lds[(l4*4 + j)*PSTR + colv] = f2bf(scr[kt][j] * sm[j]);
    }

    f32x4 ao[8] = {};
#pragma unroll
    for (int ks = 0; ks < 7; ++ks) {
      s16x8 ap = *(const s16x8*)&p_lds[l15*PSTR + ks*32 + l4*8];
#pragma unroll
      for (int dt = 0; dt < 8; ++dt) {
        const int vrow = (dt*16 + l15)*256;
        s16x8 bv = *(const s16x8*)&v_lds[vrow + (((ks*4 + l4) ^ kswz)*8)];
        ao[dt] = __builtin_amdgcn_mfma_f32_16x16x32_bf16(ap, bv, ao[dt], 0, 0, 0);
      }
    }
#pragma unroll
    for (int dt = 0; dt < 8; ++dt) {
      const int d = dt*16 + l15;
      const float av = sb[fv + d];
      const float bv = sb[HQKV + fv + d];
#pragma unroll
      for (int j = 0; j < 4; ++j) {
        int q = q0 + l4*4 + j;
        if (q < NT) {
          float v = ao[dt][j] * av + bv;
          float hs = v * fminf(fmaxf(v + 3.f, 0.f), 6.f) * (1.f/6.f);
          act[(rowBase + q)*DH + h*DV + d] = f2bf(hs);
        }
      }
    }
  }
}

// ---------------- final BN apply -> f32 out ----------------
__global__ void apply_bn(const bf16* __restrict__ y, const float* __restrict__ sb,
                         float* __restrict__ out)
{
  const int stride = gridDim.x * blockDim.x;
  for (int i = blockIdx.x * blockDim.x + threadIdx.x; i < MREAL*DIM/4; i += stride) {
    int c = (i*4) % DIM;
    u16x4 yv = *(const u16x4*)&y[(size_t)i*4];
    float4 o;
    o.x = u2f(yv.x) * sb[c]     + sb[DIM + c];
    o.y = u2f(yv.y) * sb[c + 1] + sb[DIM + c + 1];
    o.z = u2f(yv.z) * sb[c + 2] + sb[DIM + c + 2];
    o.w = u2f(yv.w) * sb[c + 3] + sb[DIM + c + 3];
    *(float4*)&out[(size_t)i*4] = o;
  }
}

extern "C" void kernel_launch(void* const* d_in, const int* in_sizes, int n_in,
                              void* d_out, int out_size, void* d_ws, size_t ws_size,
                              hipStream_t stream)
{
  const float* x      = (const float*)d_in[0];
  const float* qkv_w  = (const float*)d_in[1];
  const float* qkv_g  = (const float*)d_in[2];
  const float* qkv_b  = (const float*)d_in[3];
  const float* proj_w = (const float*)d_in[4];
  const float* proj_g = (const float*)d_in[5];
  const float* proj_b = (const float*)d_in[6];
  float* y_out   = (float*)d_out;
  float* cls_out = y_out + (size_t)MREAL * DIM;

  char* ws = (char*)d_ws;
  size_t off = 0;
  auto alloc = [&](size_t bytes) { void* p = ws + off; off += (bytes + 255) & ~(size_t)255; return p; };
  bf16* xb      = (bf16*)alloc((size_t)MPAD * DIM * 2);
  bf16* wqkvb   = (bf16*)alloc((size_t)HQKV * DIM * 2);
  bf16* wprojb  = (bf16*)alloc((size_t)DIM * DH * 2);
  bf16* qkv_raw = (bf16*)alloc((size_t)MPAD * HQKV * 2);
  bf16* act     = (bf16*)alloc((size_t)MPAD * DH * 2);
  bf16* y_raw   = (bf16*)alloc((size_t)MPAD * DIM * 2);
  bf16* vT      = (bf16*)alloc((size_t)NB * NH * DV * KPAD * 2);
  float* statq  = (float*)alloc((size_t)2 * HQKV * 4);
  float* sbq    = (float*)alloc((size_t)2 * HQKV * 4);
  float* statp  = (float*)alloc((size_t)2 * DIM * 4);
  float* sbp    = (float*)alloc((size_t)2 * DIM * 4);
  float* qcw    = (float*)alloc((size_t)NH * 128 * 4);

  prep_kernel<<<2048, 256, 0, stream>>>(x, qkv_w, proj_w, xb, wqkvb, wprojb, act, vT,
                                        statq, statp, cls_out);
  // qkv GEMM: 2400 blocks, BK=64 @ 2 blocks/CU, L2-fitting supertile order
  gemm64<DIM, HQKV/128, true, true><<<(MPAD/128)*(HQKV/128), 256, 0, stream>>>(
      xb, wqkvb, qkv_raw, vT, statq, HQKV, (MPAD/128)*(HQKV/128));
  finalize_stats<<<HQKV/256, 256, 0, stream>>>(statq, qkv_g, qkv_b, sbq, HQKV, qcw);
  // attention: one block per (b,h) = 768 blocks, K/V staged in LDS once per block
  attn_kernel<<<NB*NH, 512, 0, stream>>>(qkv_raw, vT, sbq, qcw, act, cls_out);
  // proj GEMM: 600 blocks, BK=32 @ 4 blocks/CU (all co-resident)
  gemm32<DH, DIM/128, true><<<(MPAD/128)*(DIM/128), 256, 0, stream>>>(
      act, wprojb, y_raw, statp, DIM, (MPAD/128)*(DIM/128));
  finalize_stats<<<DIM/256, 256, 0, stream>>>(statp, proj_g, proj_b, sbp, DIM, nullptr);
  apply_bn<<<2048, 256, 0, stream>>>(y_raw, sbp, y_out);
}